// Round 13
// baseline (135.511 us; speedup 1.0000x reference)
//
#include <hip/hip_runtime.h>
#include <hip/hip_bf16.h>
#include <stdint.h>

#define HIDDEN 128
#define EPG 8        // edges per 16-lane group
#define NBLK_SORT 256
#define NBUK 256

typedef __attribute__((ext_vector_type(8))) short bf16x8;
typedef __attribute__((ext_vector_type(16))) float f32x16;

static __device__ __forceinline__ uint32_t cvt2(float a, float b) {
    union { __hip_bfloat162 h2; uint32_t u; } c;
    c.h2 = __float22bfloat162_rn(make_float2(a, b));
    return c.u;
}
static __device__ __forceinline__ float bf_lo(uint32_t p) {
    union { uint32_t u; float f; } v; v.u = p << 16; return v.f;
}
static __device__ __forceinline__ float bf_hi(uint32_t p) {
    union { uint32_t u; float f; } v; v.u = p & 0xffff0000u; return v.f;
}

// ---------------- kernel 0: W1 -> Wt (transposed bf16) ----------------
__global__ __launch_bounds__(256) void transpose_w1(
    const float* __restrict__ W1, unsigned short* __restrict__ Wt)
{
    const int t = blockIdx.x * 256 + threadIdx.x;   // 4096 total
    if (t >= 4096) return;
    const int cc = t >> 4;
    const int kg = t & 15;
    const int ccol = cc & 127;
    const int kofs = (cc >= 128) ? 128 : 0;
    uint32_t u[4];
    #pragma unroll
    for (int p = 0; p < 4; ++p) {
        const float a = W1[(size_t)(kofs + kg * 8 + 2 * p) * 128 + ccol];
        const float b = W1[(size_t)(kofs + kg * 8 + 2 * p + 1) * 128 + ccol];
        u[p] = cvt2(a, b);
    }
    uint4 o = { u[0], u[1], u[2], u[3] };
    *reinterpret_cast<uint4*>(Wt + (size_t)cc * 128 + kg * 8) = o;
}

// ---------------- precompute: UV = z @ Bm + b1 (u-half) ----------------
__global__ __launch_bounds__(256) void precompute_mfma32(
    const float* __restrict__ z, const float* __restrict__ W1,
    const unsigned short* __restrict__ Wt,
    const float* __restrict__ b1,
    unsigned short* __restrict__ UV, int n_nodes, int n_groups)
{
    __shared__ char Zt[32 * 256];
    __shared__ char Sm[32 * 512];

    const int tid = threadIdx.x;
    const int lane = tid & 63;
    const int w = tid >> 6;
    const int nl = lane & 31;
    const int hi = lane >> 5;

    const int st_node = tid >> 3;
    const int st_j2 = tid & 7;
    const int st_swz = (st_node & 7) << 4;
    const int st_addrA = st_node * 256 + ((st_j2 * 32) ^ st_swz);
    const int st_addrB = st_node * 256 + ((st_j2 * 32 + 16) ^ st_swz);

    bf16x8 wf[2][8];
    if (Wt) {
        #pragma unroll
        for (int cg = 0; cg < 2; ++cg) {
            const int cc = w * 64 + cg * 32 + nl;
            #pragma unroll
            for (int ks = 0; ks < 8; ++ks)
                wf[cg][ks] = *reinterpret_cast<const bf16x8*>(
                    Wt + (size_t)cc * 128 + ks * 16 + hi * 8);
        }
    } else {
        #pragma unroll
        for (int cg = 0; cg < 2; ++cg) {
            const int cc = w * 64 + cg * 32 + nl;
            const int ccol = cc & 127;
            const int kofs = (cc >= 128) ? 128 : 0;
            #pragma unroll
            for (int ks = 0; ks < 8; ++ks) {
                const int k0 = ks * 16 + hi * 8 + kofs;
                float t[8];
                #pragma unroll
                for (int j = 0; j < 8; ++j)
                    t[j] = W1[(size_t)(k0 + j) * 128 + ccol];
                union { uint32_t u[4]; bf16x8 v; } fu;
                fu.u[0] = cvt2(t[0], t[1]); fu.u[1] = cvt2(t[2], t[3]);
                fu.u[2] = cvt2(t[4], t[5]); fu.u[3] = cvt2(t[6], t[7]);
                wf[cg][ks] = fu.v;
            }
        }
    }

    // accumulator init = b1 (u-half cols, cc<128) or 0 (v-half).
    // D row = (reg&3) + 8*(reg>>2) + 4*hi; col cc = w*64 + cg*32 + row.
    f32x16 binit[2];
    #pragma unroll
    for (int cg = 0; cg < 2; ++cg) {
        const int cc0 = w * 64 + cg * 32;
        #pragma unroll
        for (int r = 0; r < 16; ++r) {
            const int crow = (r & 3) + 8 * (r >> 2) + 4 * hi;
            const int cc = cc0 + crow;
            binit[cg][r] = (cc < 128) ? b1[cc] : 0.f;
        }
    }

    const int stride = gridDim.x;
    int ng = blockIdx.x;
    if (ng >= n_groups) return;

    float4 nz0, nz1, nz2, nz3;
    {
        int node = ng * 32 + st_node;
        node = (node < n_nodes) ? node : (n_nodes - 1);
        const float* zp = z + (size_t)node * HIDDEN + st_j2 * 16;
        nz0 = *reinterpret_cast<const float4*>(zp);
        nz1 = *reinterpret_cast<const float4*>(zp + 4);
        nz2 = *reinterpret_cast<const float4*>(zp + 8);
        nz3 = *reinterpret_cast<const float4*>(zp + 12);
    }

    while (ng < n_groups) {
        {
            uint4 A, B;
            A.x = cvt2(nz0.x, nz0.y); A.y = cvt2(nz0.z, nz0.w);
            A.z = cvt2(nz1.x, nz1.y); A.w = cvt2(nz1.z, nz1.w);
            B.x = cvt2(nz2.x, nz2.y); B.y = cvt2(nz2.z, nz2.w);
            B.z = cvt2(nz3.x, nz3.y); B.w = cvt2(nz3.z, nz3.w);
            *reinterpret_cast<uint4*>(Zt + st_addrA) = A;
            *reinterpret_cast<uint4*>(Zt + st_addrB) = B;
        }

        const int ngn = ng + stride;
        if (ngn < n_groups) {
            int node = ngn * 32 + st_node;
            node = (node < n_nodes) ? node : (n_nodes - 1);
            const float* zp = z + (size_t)node * HIDDEN + st_j2 * 16;
            nz0 = *reinterpret_cast<const float4*>(zp);
            nz1 = *reinterpret_cast<const float4*>(zp + 4);
            nz2 = *reinterpret_cast<const float4*>(zp + 8);
            nz3 = *reinterpret_cast<const float4*>(zp + 12);
        }

        __syncthreads();

        {
            const int rd_swz = (nl & 7) << 4;
            bf16x8 zf[8];
            #pragma unroll
            for (int ks = 0; ks < 8; ++ks) {
                const int off = ks * 32 + hi * 16;
                zf[ks] = *reinterpret_cast<const bf16x8*>(
                    Zt + nl * 256 + (off ^ rd_swz));
            }

            f32x16 acc0 = binit[0];
            f32x16 acc1 = binit[1];
            #pragma unroll
            for (int ks = 0; ks < 8; ++ks) {
                acc0 = __builtin_amdgcn_mfma_f32_32x32x16_bf16(wf[0][ks], zf[ks], acc0, 0, 0, 0);
                acc1 = __builtin_amdgcn_mfma_f32_32x32x16_bf16(wf[1][ks], zf[ks], acc1, 0, 0, 0);
            }

            const int swz = (nl & 15) << 3;
            #pragma unroll
            for (int g = 0; g < 4; ++g) {
                uint2 s0, s1;
                s0.x = cvt2(acc0[4 * g + 0], acc0[4 * g + 1]);
                s0.y = cvt2(acc0[4 * g + 2], acc0[4 * g + 3]);
                s1.x = cvt2(acc1[4 * g + 0], acc1[4 * g + 1]);
                s1.y = cvt2(acc1[4 * g + 2], acc1[4 * g + 3]);
                const int colb0 = w * 128 + g * 16 + hi * 8;
                const int colb1 = w * 128 + 64 + g * 16 + hi * 8;
                *reinterpret_cast<uint2*>(Sm + nl * 512 + (colb0 ^ swz)) = s0;
                *reinterpret_cast<uint2*>(Sm + nl * 512 + (colb1 ^ swz)) = s1;
            }
        }

        __syncthreads();

        {
            const int colb0 = (tid & 31) * 16;
            #pragma unroll
            for (int rep = 0; rep < 4; ++rep) {
                const int node_local = rep * 8 + (tid >> 5);
                const int swz = (node_local & 15) << 3;
                const uint2 g0 = *reinterpret_cast<const uint2*>(Sm + node_local * 512 + ((colb0) ^ swz));
                const uint2 g1 = *reinterpret_cast<const uint2*>(Sm + node_local * 512 + ((colb0 + 8) ^ swz));
                const int node = ng * 32 + node_local;
                if (node < n_nodes) {
                    uint4 o = { g0.x, g0.y, g1.x, g1.y };
                    *reinterpret_cast<uint4*>(UV + (size_t)node * 256 + (tid & 31) * 8) = o;
                }
            }
        }

        ng = ngn;
    }
}

// ---------------- counting sort by bucket = src >> sh ----------------
__global__ __launch_bounds__(256) void hist2(
    const int* __restrict__ ei, int* __restrict__ h,
    int n_edges, int chunk, int sh)
{
    __shared__ int lh[NBUK];
    const int t = threadIdx.x;
    if (t < NBUK) lh[t] = 0;
    __syncthreads();
    const int e0 = blockIdx.x * chunk;
    const int e1 = min(e0 + chunk, n_edges);
    for (int e = e0 + t; e < e1; e += 256)
        atomicAdd(&lh[((unsigned)ei[e]) >> sh], 1);
    __syncthreads();
    if (t < NBUK) h[t * NBLK_SORT + blockIdx.x] = lh[t];
}

// per-bucket row scan: h[b][0..NBLK) -> exclusive; rowtot[b] = row sum
__global__ __launch_bounds__(NBLK_SORT) void scanP1(
    int* __restrict__ h, int* __restrict__ rowtot)
{
    __shared__ int s[NBLK_SORT];
    const int b = blockIdx.x, t = threadIdx.x;
    const int v = h[b * NBLK_SORT + t];
    s[t] = v;
    __syncthreads();
    for (int d = 1; d < NBLK_SORT; d <<= 1) {
        const int x = (t >= d) ? s[t - d] : 0;
        __syncthreads();
        s[t] += x;
        __syncthreads();
    }
    h[b * NBLK_SORT + t] = s[t] - v;   // exclusive within row
    if (t == NBLK_SORT - 1) rowtot[b] = s[t];
}

// scatter: bucket base computed in-block (scanP2 folded in)
__global__ __launch_bounds__(256) void scatter2(
    const int* __restrict__ ei, const int* __restrict__ h,
    const int* __restrict__ rowtot,
    int2* __restrict__ sd, int* __restrict__ org,
    int n_edges, int chunk, int sh)
{
    __shared__ int sscan[NBUK];
    __shared__ int lbase[NBUK];
    __shared__ int lrank[NBUK];
    const int t = threadIdx.x;
    const int v = (t < NBUK) ? rowtot[t] : 0;
    if (t < NBUK) sscan[t] = v;
    __syncthreads();
    for (int d = 1; d < NBUK; d <<= 1) {
        int x = 0;
        if (t < NBUK && t >= d) x = sscan[t - d];
        __syncthreads();
        if (t < NBUK) sscan[t] += x;
        __syncthreads();
    }
    if (t < NBUK) {
        lbase[t] = (sscan[t] - v) + h[t * NBLK_SORT + blockIdx.x];
        lrank[t] = 0;
    }
    __syncthreads();
    const int e0 = blockIdx.x * chunk;
    const int e1 = min(e0 + chunk, n_edges);
    for (int e = e0 + t; e < e1; e += 256) {
        const int s = ei[e];
        const int d = ei[n_edges + e];
        const int b = ((unsigned)s) >> sh;
        const int r = atomicAdd(&lrank[b], 1);    // LDS returning (cheap)
        const int pos = lbase[b] + r;
        sd[pos] = make_int2(s, d);
        org[pos] = e;
    }
}

// ---------------- edge scoring ----------------
// score[e] = sum_j relu(u'[src][j] + v[dst][j]) * W2[j] + b2   (u' has b1)
static __device__ __forceinline__ float dot8(uint4 u, uint4 v, const float* w) {
    const uint32_t up[4] = { u.x, u.y, u.z, u.w };
    const uint32_t vp[4] = { v.x, v.y, v.z, v.w };
    float s = 0.f;
    #pragma unroll
    for (int p = 0; p < 4; ++p) {
        const float h0 = bf_lo(up[p]) + bf_lo(vp[p]);
        const float h1 = bf_hi(up[p]) + bf_hi(vp[p]);
        s = fmaf(fmaxf(h0, 0.f), w[2 * p], s);
        s = fmaf(fmaxf(h1, 0.f), w[2 * p + 1], s);
    }
    return s;
}
static __device__ __forceinline__ float red16(float s) {
    s += __shfl_xor(s, 1, 64); s += __shfl_xor(s, 2, 64);
    s += __shfl_xor(s, 4, 64); s += __shfl_xor(s, 8, 64);
    return s;
}

// PACKED=1: edges from int2 sd[] (sorted), scores scattered to out[org[e]].
// PACKED=0: direct fallback from srcp/dstp columns, out[e].
template <int PACKED>
__global__ __launch_bounds__(256, 4) void edge_score_t(
    const int2* __restrict__ sd, const int* __restrict__ org,
    const int* __restrict__ srcp, const int* __restrict__ dstp,
    const unsigned short* __restrict__ UV,
    const float* __restrict__ W2,
    const float* __restrict__ b2, float* __restrict__ outp, int n_edges)
{
    int vb = blockIdx.x;
    if (PACKED) {   // chunked bijective XCD swizzle (m204)
        const int nb = gridDim.x;
        const int q8 = nb >> 3, r8 = nb & 7;
        const int x = blockIdx.x & 7, i = blockIdx.x >> 3;
        vb = (x < r8 ? x * (q8 + 1) : r8 * (q8 + 1) + (x - r8) * q8) + i;
    }

    const int g = (vb * 256 + (int)threadIdx.x) >> 4;
    const int q = threadIdx.x & 15;
    const int e0 = g * EPG;
    if (e0 >= n_edges) return;

    const float4 w2a = *reinterpret_cast<const float4*>(W2 + q * 8);
    const float4 w2b = *reinterpret_cast<const float4*>(W2 + q * 8 + 4);
    const float wloc[8] = { w2a.x, w2a.y, w2a.z, w2a.w, w2b.x, w2b.y, w2b.z, w2b.w };
    const float bias = b2[0];

    const char* UVb = (const char*)UV;
    const uint32_t qo = (uint32_t)q * 16u;

    if (e0 + EPG - 1 < n_edges) {
        int sidx[EPG], didx[EPG];
        if (PACKED) {
            const int4 p0 = *reinterpret_cast<const int4*>(sd + e0);
            const int4 p1 = *reinterpret_cast<const int4*>(sd + e0 + 2);
            const int4 p2 = *reinterpret_cast<const int4*>(sd + e0 + 4);
            const int4 p3 = *reinterpret_cast<const int4*>(sd + e0 + 6);
            sidx[0]=p0.x; didx[0]=p0.y; sidx[1]=p0.z; didx[1]=p0.w;
            sidx[2]=p1.x; didx[2]=p1.y; sidx[3]=p1.z; didx[3]=p1.w;
            sidx[4]=p2.x; didx[4]=p2.y; sidx[5]=p2.z; didx[5]=p2.w;
            sidx[6]=p3.x; didx[6]=p3.y; sidx[7]=p3.z; didx[7]=p3.w;
        } else {
            const int4 sA = *reinterpret_cast<const int4*>(srcp + e0);
            const int4 sB = *reinterpret_cast<const int4*>(srcp + e0 + 4);
            const int4 dA = *reinterpret_cast<const int4*>(dstp + e0);
            const int4 dB = *reinterpret_cast<const int4*>(dstp + e0 + 4);
            sidx[0]=sA.x; sidx[1]=sA.y; sidx[2]=sA.z; sidx[3]=sA.w;
            sidx[4]=sB.x; sidx[5]=sB.y; sidx[6]=sB.z; sidx[7]=sB.w;
            didx[0]=dA.x; didx[1]=dA.y; didx[2]=dA.z; didx[3]=dA.w;
            didx[4]=dB.x; didx[5]=dB.y; didx[6]=dB.z; didx[7]=dB.w;
        }

        uint4 u[EPG], v[EPG];
        #pragma unroll
        for (int ii = 0; ii < EPG; ++ii) {
            u[ii] = *reinterpret_cast<const uint4*>(UVb + ((uint32_t)sidx[ii] * 512u + qo));
            v[ii] = *reinterpret_cast<const uint4*>(UVb + ((uint32_t)didx[ii] * 512u + 256u + qo));
        }
        __builtin_amdgcn_sched_barrier(0);

        float s[EPG];
        #pragma unroll
        for (int ii = 0; ii < EPG; ++ii) s[ii] = dot8(u[ii], v[ii], wloc);
        #pragma unroll
        for (int ii = 0; ii < EPG; ++ii) s[ii] = red16(s[ii]) + bias;

        if (q == 0) {
            if (PACKED) {
                const int4 o0 = *reinterpret_cast<const int4*>(org + e0);
                const int4 o1 = *reinterpret_cast<const int4*>(org + e0 + 4);
                outp[o0.x] = s[0]; outp[o0.y] = s[1];
                outp[o0.z] = s[2]; outp[o0.w] = s[3];
                outp[o1.x] = s[4]; outp[o1.y] = s[5];
                outp[o1.z] = s[6]; outp[o1.w] = s[7];
            } else {
                float4 oA = { s[0], s[1], s[2], s[3] };
                float4 oB = { s[4], s[5], s[6], s[7] };
                *reinterpret_cast<float4*>(outp + e0) = oA;
                *reinterpret_cast<float4*>(outp + e0 + 4) = oB;
            }
        }
    } else {
        for (int ii = 0; ii < EPG; ++ii) {
            const int e = e0 + ii;
            if (e >= n_edges) break;
            const int si = PACKED ? sd[e].x : srcp[e];
            const int di = PACKED ? sd[e].y : dstp[e];
            const uint4 uu = *reinterpret_cast<const uint4*>(UVb + ((uint32_t)si * 512u + qo));
            const uint4 vv = *reinterpret_cast<const uint4*>(UVb + ((uint32_t)di * 512u + 256u + qo));
            float s = red16(dot8(uu, vv, wloc));
            if (q == 0) {
                if (PACKED) outp[org[e]] = s + bias;
                else        outp[e] = s + bias;
            }
        }
    }
}

extern "C" void kernel_launch(void* const* d_in, const int* in_sizes, int n_in,
                              void* d_out, int out_size, void* d_ws, size_t ws_size,
                              hipStream_t stream) {
    const float* z  = (const float*)d_in[0];
    const int*   ei = (const int*)d_in[1];
    const float* W1 = (const float*)d_in[2];
    const float* b1 = (const float*)d_in[3];
    const float* W2 = (const float*)d_in[4];
    const float* b2 = (const float*)d_in[5];
    float* out = (float*)d_out;

    const int n_nodes = in_sizes[0] / HIDDEN;
    const int n_edges = in_sizes[1] / 2;

    // bucket shift: smallest sh with (n_nodes-1)>>sh < NBUK
    int sh = 0;
    while (((unsigned)(n_nodes - 1) >> sh) >= NBUK) sh++;

    // ---- workspace layout ----
    char* wsp = (char*)d_ws;
    size_t off = 0;
    auto alloc = [&](size_t bytes) -> char* {
        char* p = wsp + off;
        off = (off + bytes + 255) & ~(size_t)255;
        return p;
    };
    unsigned short* UV = (unsigned short*)alloc((size_t)n_nodes * 256 * 2);
    unsigned short* Wt = (unsigned short*)alloc(256 * 128 * 2);
    const size_t base_need = off;
    int*  h      = (int*)alloc((size_t)NBUK * NBLK_SORT * 4);
    int*  rowtot = (int*)alloc((size_t)NBUK * 4);
    int2* sd     = (int2*)alloc((size_t)n_edges * 8);
    int*  org    = (int*)alloc((size_t)n_edges * 4);
    const bool have_wt = ws_size >= base_need;
    const bool do_sort = ws_size >= off;

    if (have_wt) transpose_w1<<<16, 256, 0, stream>>>(W1, Wt);

    {
        const int n_groups = (n_nodes + 31) / 32;
        const int g1 = n_groups < 1024 ? n_groups : 1024;
        precompute_mfma32<<<g1, 256, 0, stream>>>(z, W1, have_wt ? Wt : nullptr,
                                                  b1, UV, n_nodes, n_groups);
    }

    const int groups = (n_edges + EPG - 1) / EPG;
    const int eblocks = (groups * 16 + 255) / 256;

    if (do_sort) {
        const int chunk = (n_edges + NBLK_SORT - 1) / NBLK_SORT;
        hist2<<<NBLK_SORT, 256, 0, stream>>>(ei, h, n_edges, chunk, sh);
        scanP1<<<NBUK, NBLK_SORT, 0, stream>>>(h, rowtot);
        scatter2<<<NBLK_SORT, 256, 0, stream>>>(ei, h, rowtot, sd, org,
                                                n_edges, chunk, sh);
        edge_score_t<1><<<eblocks, 256, 0, stream>>>(sd, org, nullptr, nullptr, UV,
                                                     W2, b2, out, n_edges);
    } else {
        edge_score_t<0><<<eblocks, 256, 0, stream>>>(nullptr, nullptr, ei, ei + n_edges,
                                                     UV, W2, b2, out, n_edges);
    }
}

// Round 14
// 128.770 us; speedup vs baseline: 1.0523x; 1.0523x over previous
//
#include <hip/hip_runtime.h>
#include <hip/hip_bf16.h>
#include <stdint.h>

#define HIDDEN 128
#define EPG 8        // edges per 16-lane group
#define NBLK_SORT 256
#define NBUK 256

typedef __attribute__((ext_vector_type(8))) short bf16x8;
typedef __attribute__((ext_vector_type(16))) float f32x16;

static __device__ __forceinline__ uint32_t cvt2(float a, float b) {
    union { __hip_bfloat162 h2; uint32_t u; } c;
    c.h2 = __float22bfloat162_rn(make_float2(a, b));
    return c.u;
}
static __device__ __forceinline__ float bf_lo(uint32_t p) {
    union { uint32_t u; float f; } v; v.u = p << 16; return v.f;
}
static __device__ __forceinline__ float bf_hi(uint32_t p) {
    union { uint32_t u; float f; } v; v.u = p & 0xffff0000u; return v.f;
}

// ---------------- K1: hist2 (blocks 0..255)  ||  W1->Wt transpose (256..271) ----
__global__ __launch_bounds__(256) void k1_hist_transpose(
    const int* __restrict__ ei, int* __restrict__ h,
    int n_edges, int chunk, int sh,
    const float* __restrict__ W1, unsigned short* __restrict__ Wt)
{
    __shared__ int lh[NBUK];
    if (blockIdx.x < NBLK_SORT) {
        const int t = threadIdx.x;
        if (t < NBUK) lh[t] = 0;
        __syncthreads();
        const int e0 = blockIdx.x * chunk;
        const int e1 = min(e0 + chunk, n_edges);
        for (int e = e0 + t; e < e1; e += 256)
            atomicAdd(&lh[((unsigned)ei[e]) >> sh], 1);
        __syncthreads();
        if (t < NBUK) h[t * NBLK_SORT + blockIdx.x] = lh[t];
    } else {
        const int t = (blockIdx.x - NBLK_SORT) * 256 + threadIdx.x;  // 0..4095
        if (t >= 4096) return;
        const int cc = t >> 4;
        const int kg = t & 15;
        const int ccol = cc & 127;
        const int kofs = (cc >= 128) ? 128 : 0;
        uint32_t u[4];
        #pragma unroll
        for (int p = 0; p < 4; ++p) {
            const float a = W1[(size_t)(kofs + kg * 8 + 2 * p) * 128 + ccol];
            const float b = W1[(size_t)(kofs + kg * 8 + 2 * p + 1) * 128 + ccol];
            u[p] = cvt2(a, b);
        }
        uint4 o = { u[0], u[1], u[2], u[3] };
        *reinterpret_cast<uint4*>(Wt + (size_t)cc * 128 + kg * 8) = o;
    }
}

// ---------------- K2: scanP1 (blocks 0..255)  ||  precompute (256..) ----------
// precompute: UV[n][cc] = sum_k z[n][k]*Bm[k][cc] + b1[cc] (u-half), bf16 out.
__global__ __launch_bounds__(256) void k2_scan_precompute(
    int* __restrict__ h, int* __restrict__ rowtot,
    const float* __restrict__ z, const unsigned short* __restrict__ Wt,
    const float* __restrict__ b1,
    unsigned short* __restrict__ UV, int n_nodes, int n_groups)
{
    __shared__ char Zt[32 * 256];
    __shared__ char Sm[32 * 512];
    __shared__ int ss[NBLK_SORT];

    if (blockIdx.x < NBUK) {
        // ---- scanP1 role: exclusive scan of h[b][0..NBLK), rowtot[b]=sum ----
        const int b = blockIdx.x, t = threadIdx.x;
        const int v = h[b * NBLK_SORT + t];
        ss[t] = v;
        __syncthreads();
        for (int d = 1; d < NBLK_SORT; d <<= 1) {
            const int x = (t >= d) ? ss[t - d] : 0;
            __syncthreads();
            ss[t] += x;
            __syncthreads();
        }
        h[b * NBLK_SORT + t] = ss[t] - v;
        if (t == NBLK_SORT - 1) rowtot[b] = ss[t];
        return;
    }

    // ---- precompute role ----
    const int tid = threadIdx.x;
    const int lane = tid & 63;
    const int w = tid >> 6;
    const int nl = lane & 31;
    const int hi = lane >> 5;

    const int st_node = tid >> 3;
    const int st_j2 = tid & 7;
    const int st_swz = (st_node & 7) << 4;
    const int st_addrA = st_node * 256 + ((st_j2 * 32) ^ st_swz);
    const int st_addrB = st_node * 256 + ((st_j2 * 32 + 16) ^ st_swz);

    bf16x8 wf[2][8];
    #pragma unroll
    for (int cg = 0; cg < 2; ++cg) {
        const int cc = w * 64 + cg * 32 + nl;
        #pragma unroll
        for (int ks = 0; ks < 8; ++ks)
            wf[cg][ks] = *reinterpret_cast<const bf16x8*>(
                Wt + (size_t)cc * 128 + ks * 16 + hi * 8);
    }

    // accumulator init = b1 (u-half cols, cc<128) or 0 (v-half)
    f32x16 binit[2];
    #pragma unroll
    for (int cg = 0; cg < 2; ++cg) {
        const int cc0 = w * 64 + cg * 32;
        #pragma unroll
        for (int r = 0; r < 16; ++r) {
            const int crow = (r & 3) + 8 * (r >> 2) + 4 * hi;
            const int cc = cc0 + crow;
            binit[cg][r] = (cc < 128) ? b1[cc] : 0.f;
        }
    }

    const int stride = gridDim.x - NBUK;
    int ng = blockIdx.x - NBUK;
    if (ng >= n_groups) return;

    float4 nz0, nz1, nz2, nz3;
    {
        int node = ng * 32 + st_node;
        node = (node < n_nodes) ? node : (n_nodes - 1);
        const float* zp = z + (size_t)node * HIDDEN + st_j2 * 16;
        nz0 = *reinterpret_cast<const float4*>(zp);
        nz1 = *reinterpret_cast<const float4*>(zp + 4);
        nz2 = *reinterpret_cast<const float4*>(zp + 8);
        nz3 = *reinterpret_cast<const float4*>(zp + 12);
    }

    while (ng < n_groups) {
        {
            uint4 A, B;
            A.x = cvt2(nz0.x, nz0.y); A.y = cvt2(nz0.z, nz0.w);
            A.z = cvt2(nz1.x, nz1.y); A.w = cvt2(nz1.z, nz1.w);
            B.x = cvt2(nz2.x, nz2.y); B.y = cvt2(nz2.z, nz2.w);
            B.z = cvt2(nz3.x, nz3.y); B.w = cvt2(nz3.z, nz3.w);
            *reinterpret_cast<uint4*>(Zt + st_addrA) = A;
            *reinterpret_cast<uint4*>(Zt + st_addrB) = B;
        }

        const int ngn = ng + stride;
        if (ngn < n_groups) {
            int node = ngn * 32 + st_node;
            node = (node < n_nodes) ? node : (n_nodes - 1);
            const float* zp = z + (size_t)node * HIDDEN + st_j2 * 16;
            nz0 = *reinterpret_cast<const float4*>(zp);
            nz1 = *reinterpret_cast<const float4*>(zp + 4);
            nz2 = *reinterpret_cast<const float4*>(zp + 8);
            nz3 = *reinterpret_cast<const float4*>(zp + 12);
        }

        __syncthreads();

        {
            const int rd_swz = (nl & 7) << 4;
            bf16x8 zf[8];
            #pragma unroll
            for (int ks = 0; ks < 8; ++ks) {
                const int off = ks * 32 + hi * 16;
                zf[ks] = *reinterpret_cast<const bf16x8*>(
                    Zt + nl * 256 + (off ^ rd_swz));
            }

            f32x16 acc0 = binit[0];
            f32x16 acc1 = binit[1];
            #pragma unroll
            for (int ks = 0; ks < 8; ++ks) {
                acc0 = __builtin_amdgcn_mfma_f32_32x32x16_bf16(wf[0][ks], zf[ks], acc0, 0, 0, 0);
                acc1 = __builtin_amdgcn_mfma_f32_32x32x16_bf16(wf[1][ks], zf[ks], acc1, 0, 0, 0);
            }

            const int swz = (nl & 15) << 3;
            #pragma unroll
            for (int g = 0; g < 4; ++g) {
                uint2 s0, s1;
                s0.x = cvt2(acc0[4 * g + 0], acc0[4 * g + 1]);
                s0.y = cvt2(acc0[4 * g + 2], acc0[4 * g + 3]);
                s1.x = cvt2(acc1[4 * g + 0], acc1[4 * g + 1]);
                s1.y = cvt2(acc1[4 * g + 2], acc1[4 * g + 3]);
                const int colb0 = w * 128 + g * 16 + hi * 8;
                const int colb1 = w * 128 + 64 + g * 16 + hi * 8;
                *reinterpret_cast<uint2*>(Sm + nl * 512 + (colb0 ^ swz)) = s0;
                *reinterpret_cast<uint2*>(Sm + nl * 512 + (colb1 ^ swz)) = s1;
            }
        }

        __syncthreads();

        {
            const int colb0 = (tid & 31) * 16;
            #pragma unroll
            for (int rep = 0; rep < 4; ++rep) {
                const int node_local = rep * 8 + (tid >> 5);
                const int swz = (node_local & 15) << 3;
                const uint2 g0 = *reinterpret_cast<const uint2*>(Sm + node_local * 512 + ((colb0) ^ swz));
                const uint2 g1 = *reinterpret_cast<const uint2*>(Sm + node_local * 512 + ((colb0 + 8) ^ swz));
                const int node = ng * 32 + node_local;
                if (node < n_nodes) {
                    uint4 o = { g0.x, g0.y, g1.x, g1.y };
                    *reinterpret_cast<uint4*>(UV + (size_t)node * 256 + (tid & 31) * 8) = o;
                }
            }
        }

        ng = ngn;
    }
}

// ---------------- scatter (bucket bases scanned in-block) ----------------
__global__ __launch_bounds__(256) void scatter2(
    const int* __restrict__ ei, const int* __restrict__ h,
    const int* __restrict__ rowtot,
    int2* __restrict__ sd, int* __restrict__ org,
    int n_edges, int chunk, int sh)
{
    __shared__ int sscan[NBUK];
    __shared__ int lbase[NBUK];
    __shared__ int lrank[NBUK];
    const int t = threadIdx.x;
    const int v = (t < NBUK) ? rowtot[t] : 0;
    if (t < NBUK) sscan[t] = v;
    __syncthreads();
    for (int d = 1; d < NBUK; d <<= 1) {
        int x = 0;
        if (t < NBUK && t >= d) x = sscan[t - d];
        __syncthreads();
        if (t < NBUK) sscan[t] += x;
        __syncthreads();
    }
    if (t < NBUK) {
        lbase[t] = (sscan[t] - v) + h[t * NBLK_SORT + blockIdx.x];
        lrank[t] = 0;
    }
    __syncthreads();
    const int e0 = blockIdx.x * chunk;
    const int e1 = min(e0 + chunk, n_edges);
    for (int e = e0 + t; e < e1; e += 256) {
        const int s = ei[e];
        const int d = ei[n_edges + e];
        const int b = ((unsigned)s) >> sh;
        const int r = atomicAdd(&lrank[b], 1);
        const int pos = lbase[b] + r;
        sd[pos] = make_int2(s, d);
        org[pos] = e;
    }
}

// ---------------- edge scoring ----------------
// score[e] = sum_j relu(u'[src][j] + v[dst][j]) * W2[j] + b2   (u' has b1)
static __device__ __forceinline__ float dot8(uint4 u, uint4 v, const float* w) {
    const uint32_t up[4] = { u.x, u.y, u.z, u.w };
    const uint32_t vp[4] = { v.x, v.y, v.z, v.w };
    float s = 0.f;
    #pragma unroll
    for (int p = 0; p < 4; ++p) {
        const float h0 = bf_lo(up[p]) + bf_lo(vp[p]);
        const float h1 = bf_hi(up[p]) + bf_hi(vp[p]);
        s = fmaf(fmaxf(h0, 0.f), w[2 * p], s);
        s = fmaf(fmaxf(h1, 0.f), w[2 * p + 1], s);
    }
    return s;
}
static __device__ __forceinline__ float red16(float s) {
    s += __shfl_xor(s, 1, 64); s += __shfl_xor(s, 2, 64);
    s += __shfl_xor(s, 4, 64); s += __shfl_xor(s, 8, 64);
    return s;
}

template <int PACKED>
__global__ __launch_bounds__(256, 4) void edge_score_t(
    const int2* __restrict__ sd, const int* __restrict__ org,
    const int* __restrict__ srcp, const int* __restrict__ dstp,
    const unsigned short* __restrict__ UV,
    const float* __restrict__ W2,
    const float* __restrict__ b2, float* __restrict__ outp, int n_edges)
{
    int vb = blockIdx.x;
    if (PACKED) {   // chunked bijective XCD swizzle (m204)
        const int nb = gridDim.x;
        const int q8 = nb >> 3, r8 = nb & 7;
        const int x = blockIdx.x & 7, i = blockIdx.x >> 3;
        vb = (x < r8 ? x * (q8 + 1) : r8 * (q8 + 1) + (x - r8) * q8) + i;
    }

    const int g = (vb * 256 + (int)threadIdx.x) >> 4;
    const int q = threadIdx.x & 15;
    const int e0 = g * EPG;
    if (e0 >= n_edges) return;

    const float4 w2a = *reinterpret_cast<const float4*>(W2 + q * 8);
    const float4 w2b = *reinterpret_cast<const float4*>(W2 + q * 8 + 4);
    const float wloc[8] = { w2a.x, w2a.y, w2a.z, w2a.w, w2b.x, w2b.y, w2b.z, w2b.w };
    const float bias = b2[0];

    const char* UVb = (const char*)UV;
    const uint32_t qo = (uint32_t)q * 16u;

    if (e0 + EPG - 1 < n_edges) {
        int sidx[EPG], didx[EPG];
        if (PACKED) {
            const int4 p0 = *reinterpret_cast<const int4*>(sd + e0);
            const int4 p1 = *reinterpret_cast<const int4*>(sd + e0 + 2);
            const int4 p2 = *reinterpret_cast<const int4*>(sd + e0 + 4);
            const int4 p3 = *reinterpret_cast<const int4*>(sd + e0 + 6);
            sidx[0]=p0.x; didx[0]=p0.y; sidx[1]=p0.z; didx[1]=p0.w;
            sidx[2]=p1.x; didx[2]=p1.y; sidx[3]=p1.z; didx[3]=p1.w;
            sidx[4]=p2.x; didx[4]=p2.y; sidx[5]=p2.z; didx[5]=p2.w;
            sidx[6]=p3.x; didx[6]=p3.y; sidx[7]=p3.z; didx[7]=p3.w;
        } else {
            const int4 sA = *reinterpret_cast<const int4*>(srcp + e0);
            const int4 sB = *reinterpret_cast<const int4*>(srcp + e0 + 4);
            const int4 dA = *reinterpret_cast<const int4*>(dstp + e0);
            const int4 dB = *reinterpret_cast<const int4*>(dstp + e0 + 4);
            sidx[0]=sA.x; sidx[1]=sA.y; sidx[2]=sA.z; sidx[3]=sA.w;
            sidx[4]=sB.x; sidx[5]=sB.y; sidx[6]=sB.z; sidx[7]=sB.w;
            didx[0]=dA.x; didx[1]=dA.y; didx[2]=dA.z; didx[3]=dA.w;
            didx[4]=dB.x; didx[5]=dB.y; didx[6]=dB.z; didx[7]=dB.w;
        }

        uint4 u[EPG], v[EPG];
        #pragma unroll
        for (int ii = 0; ii < EPG; ++ii) {
            u[ii] = *reinterpret_cast<const uint4*>(UVb + ((uint32_t)sidx[ii] * 512u + qo));
            v[ii] = *reinterpret_cast<const uint4*>(UVb + ((uint32_t)didx[ii] * 512u + 256u + qo));
        }
        __builtin_amdgcn_sched_barrier(0);

        float s[EPG];
        #pragma unroll
        for (int ii = 0; ii < EPG; ++ii) s[ii] = dot8(u[ii], v[ii], wloc);
        #pragma unroll
        for (int ii = 0; ii < EPG; ++ii) s[ii] = red16(s[ii]) + bias;

        if (q == 0) {
            if (PACKED) {
                const int4 o0 = *reinterpret_cast<const int4*>(org + e0);
                const int4 o1 = *reinterpret_cast<const int4*>(org + e0 + 4);
                outp[o0.x] = s[0]; outp[o0.y] = s[1];
                outp[o0.z] = s[2]; outp[o0.w] = s[3];
                outp[o1.x] = s[4]; outp[o1.y] = s[5];
                outp[o1.z] = s[6]; outp[o1.w] = s[7];
            } else {
                float4 oA = { s[0], s[1], s[2], s[3] };
                float4 oB = { s[4], s[5], s[6], s[7] };
                *reinterpret_cast<float4*>(outp + e0) = oA;
                *reinterpret_cast<float4*>(outp + e0 + 4) = oB;
            }
        }
    } else {
        for (int ii = 0; ii < EPG; ++ii) {
            const int e = e0 + ii;
            if (e >= n_edges) break;
            const int si = PACKED ? sd[e].x : srcp[e];
            const int di = PACKED ? sd[e].y : dstp[e];
            const uint4 uu = *reinterpret_cast<const uint4*>(UVb + ((uint32_t)si * 512u + qo));
            const uint4 vv = *reinterpret_cast<const uint4*>(UVb + ((uint32_t)di * 512u + 256u + qo));
            float s = red16(dot8(uu, vv, wloc));
            if (q == 0) {
                if (PACKED) outp[org[e]] = s + bias;
                else        outp[e] = s + bias;
            }
        }
    }
}

// ---- standalone fallbacks (no-sort path) ----
__global__ __launch_bounds__(256) void transpose_w1(
    const float* __restrict__ W1, unsigned short* __restrict__ Wt)
{
    const int t = blockIdx.x * 256 + threadIdx.x;
    if (t >= 4096) return;
    const int cc = t >> 4;
    const int kg = t & 15;
    const int ccol = cc & 127;
    const int kofs = (cc >= 128) ? 128 : 0;
    uint32_t u[4];
    #pragma unroll
    for (int p = 0; p < 4; ++p) {
        const float a = W1[(size_t)(kofs + kg * 8 + 2 * p) * 128 + ccol];
        const float b = W1[(size_t)(kofs + kg * 8 + 2 * p + 1) * 128 + ccol];
        u[p] = cvt2(a, b);
    }
    uint4 o = { u[0], u[1], u[2], u[3] };
    *reinterpret_cast<uint4*>(Wt + (size_t)cc * 128 + kg * 8) = o;
}

extern "C" void kernel_launch(void* const* d_in, const int* in_sizes, int n_in,
                              void* d_out, int out_size, void* d_ws, size_t ws_size,
                              hipStream_t stream) {
    const float* z  = (const float*)d_in[0];
    const int*   ei = (const int*)d_in[1];
    const float* W1 = (const float*)d_in[2];
    const float* b1 = (const float*)d_in[3];
    const float* W2 = (const float*)d_in[4];
    const float* b2 = (const float*)d_in[5];
    float* out = (float*)d_out;

    const int n_nodes = in_sizes[0] / HIDDEN;
    const int n_edges = in_sizes[1] / 2;

    int sh = 0;
    while (((unsigned)(n_nodes - 1) >> sh) >= NBUK) sh++;

    // ---- workspace layout ----
    char* wsp = (char*)d_ws;
    size_t off = 0;
    auto alloc = [&](size_t bytes) -> char* {
        char* p = wsp + off;
        off = (off + bytes + 255) & ~(size_t)255;
        return p;
    };
    unsigned short* UV = (unsigned short*)alloc((size_t)n_nodes * 256 * 2);
    unsigned short* Wt = (unsigned short*)alloc(256 * 128 * 2);
    int*  h      = (int*)alloc((size_t)NBUK * NBLK_SORT * 4);
    int*  rowtot = (int*)alloc((size_t)NBUK * 4);
    int2* sd     = (int2*)alloc((size_t)n_edges * 8);
    int*  org    = (int*)alloc((size_t)n_edges * 4);
    const bool do_sort = ws_size >= off;

    const int n_groups = (n_nodes + 31) / 32;
    const int groups = (n_edges + EPG - 1) / EPG;
    const int eblocks = (groups * 16 + 255) / 256;

    if (do_sort) {
        const int chunk = (n_edges + NBLK_SORT - 1) / NBLK_SORT;
        // K1: hist || transpose
        k1_hist_transpose<<<NBLK_SORT + 16, 256, 0, stream>>>(
            ei, h, n_edges, chunk, sh, W1, Wt);
        // K2: scanP1 || precompute
        {
            const int pblocks = n_groups < 1024 ? n_groups : 1024;
            k2_scan_precompute<<<NBUK + pblocks, 256, 0, stream>>>(
                h, rowtot, z, Wt, b1, UV, n_nodes, n_groups);
        }
        // K3: scatter
        scatter2<<<NBLK_SORT, 256, 0, stream>>>(ei, h, rowtot, sd, org,
                                                n_edges, chunk, sh);
        // K4: edge scoring
        edge_score_t<1><<<eblocks, 256, 0, stream>>>(sd, org, nullptr, nullptr, UV,
                                                     W2, b2, out, n_edges);
    } else {
        // fallback: minimal path (requires only UV+Wt; if even that fails,
        // Wt path is still within UV-only ws because ws >= out+inputs scale)
        transpose_w1<<<16, 256, 0, stream>>>(W1, Wt);
        {
            const int pblocks = n_groups < 1024 ? n_groups : 1024;
            k2_scan_precompute<<<NBUK + pblocks, 256, 0, stream>>>(
                h, rowtot, z, Wt, b1, UV, n_nodes, n_groups);
        }
        edge_score_t<0><<<eblocks, 256, 0, stream>>>(nullptr, nullptr, ei, ei + n_edges,
                                                     UV, W2, b2, out, n_edges);
    }
}

// Round 15
// 127.552 us; speedup vs baseline: 1.0624x; 1.0096x over previous
//
#include <hip/hip_runtime.h>
#include <hip/hip_bf16.h>
#include <stdint.h>

#define HIDDEN 128
#define EPG 8        // edges per 16-lane group
#define NBLK_SORT 256
#define NBUK 256

typedef __attribute__((ext_vector_type(8))) short bf16x8;
typedef __attribute__((ext_vector_type(16))) float f32x16;

static __device__ __forceinline__ uint32_t cvt2(float a, float b) {
    union { __hip_bfloat162 h2; uint32_t u; } c;
    c.h2 = __float22bfloat162_rn(make_float2(a, b));
    return c.u;
}
static __device__ __forceinline__ float bf_lo(uint32_t p) {
    union { uint32_t u; float f; } v; v.u = p << 16; return v.f;
}
static __device__ __forceinline__ float bf_hi(uint32_t p) {
    union { uint32_t u; float f; } v; v.u = p & 0xffff0000u; return v.f;
}

// ---------------- K1: hist2 (blocks 0..255)  ||  W1->Wt transpose (256..271) ----
__global__ __launch_bounds__(256) void k1_hist_transpose(
    const int* __restrict__ ei, int* __restrict__ h,
    int n_edges, int chunk, int sh,
    const float* __restrict__ W1, unsigned short* __restrict__ Wt)
{
    __shared__ int lh[NBUK];
    if (blockIdx.x < NBLK_SORT) {
        const int t = threadIdx.x;
        if (t < NBUK) lh[t] = 0;
        __syncthreads();
        const int e0 = blockIdx.x * chunk;
        const int e1 = min(e0 + chunk, n_edges);
        for (int e = e0 + t; e < e1; e += 256)
            atomicAdd(&lh[((unsigned)ei[e]) >> sh], 1);
        __syncthreads();
        if (t < NBUK) h[t * NBLK_SORT + blockIdx.x] = lh[t];
    } else {
        const int t = (blockIdx.x - NBLK_SORT) * 256 + threadIdx.x;  // 0..4095
        if (t >= 4096) return;
        const int cc = t >> 4;
        const int kg = t & 15;
        const int ccol = cc & 127;
        const int kofs = (cc >= 128) ? 128 : 0;
        uint32_t u[4];
        #pragma unroll
        for (int p = 0; p < 4; ++p) {
            const float a = W1[(size_t)(kofs + kg * 8 + 2 * p) * 128 + ccol];
            const float b = W1[(size_t)(kofs + kg * 8 + 2 * p + 1) * 128 + ccol];
            u[p] = cvt2(a, b);
        }
        uint4 o = { u[0], u[1], u[2], u[3] };
        *reinterpret_cast<uint4*>(Wt + (size_t)cc * 128 + kg * 8) = o;
    }
}

// ---------------- K2: scanP1 (standalone, 256 blocks) --------------------
// exclusive scan of h[b][0..NBLK) per bucket row; rowtot[b] = row sum
__global__ __launch_bounds__(NBLK_SORT) void scanP1(
    int* __restrict__ h, int* __restrict__ rowtot)
{
    __shared__ int ss[NBLK_SORT];
    const int b = blockIdx.x, t = threadIdx.x;
    const int v = h[b * NBLK_SORT + t];
    ss[t] = v;
    __syncthreads();
    for (int d = 1; d < NBLK_SORT; d <<= 1) {
        const int x = (t >= d) ? ss[t - d] : 0;
        __syncthreads();
        ss[t] += x;
        __syncthreads();
    }
    h[b * NBLK_SORT + t] = ss[t] - v;
    if (t == NBLK_SORT - 1) rowtot[b] = ss[t];
}

// ---------------- K3: scatter (blocks 0..nscatter-1) || precompute (rest) ----
// scatter: sorted (src,dst) pairs + original edge id.
// precompute: UV[n][cc] = sum_k z[n][k]*Bm[k][cc] + b1[cc] (u-half), bf16.
__global__ __launch_bounds__(256) void k3_scatter_precompute(
    const int* __restrict__ ei, const int* __restrict__ h,
    const int* __restrict__ rowtot,
    int2* __restrict__ sd, int* __restrict__ org,
    int n_edges, int chunk, int sh, int nscatter,
    const float* __restrict__ z, const unsigned short* __restrict__ Wt,
    const float* __restrict__ b1,
    unsigned short* __restrict__ UV, int n_nodes, int n_groups)
{
    __shared__ char Zt[32 * 256];
    __shared__ char Sm[32 * 512];
    __shared__ int sscan[NBUK];
    __shared__ int lbase[NBUK];
    __shared__ int lrank[NBUK];

    if (blockIdx.x < (unsigned)nscatter) {
        // ---- scatter role ----
        const int t = threadIdx.x;
        const int v = (t < NBUK) ? rowtot[t] : 0;
        if (t < NBUK) sscan[t] = v;
        __syncthreads();
        for (int d = 1; d < NBUK; d <<= 1) {
            int x = 0;
            if (t < NBUK && t >= d) x = sscan[t - d];
            __syncthreads();
            if (t < NBUK) sscan[t] += x;
            __syncthreads();
        }
        if (t < NBUK) {
            lbase[t] = (sscan[t] - v) + h[t * NBLK_SORT + blockIdx.x];
            lrank[t] = 0;
        }
        __syncthreads();
        const int e0 = blockIdx.x * chunk;
        const int e1 = min(e0 + chunk, n_edges);
        for (int e = e0 + t; e < e1; e += 256) {
            const int s = ei[e];
            const int d = ei[n_edges + e];
            const int b = ((unsigned)s) >> sh;
            const int r = atomicAdd(&lrank[b], 1);
            const int pos = lbase[b] + r;
            sd[pos] = make_int2(s, d);
            org[pos] = e;
        }
        return;
    }

    // ---- precompute role ----
    const int tid = threadIdx.x;
    const int lane = tid & 63;
    const int w = tid >> 6;
    const int nl = lane & 31;
    const int hi = lane >> 5;

    const int st_node = tid >> 3;
    const int st_j2 = tid & 7;
    const int st_swz = (st_node & 7) << 4;
    const int st_addrA = st_node * 256 + ((st_j2 * 32) ^ st_swz);
    const int st_addrB = st_node * 256 + ((st_j2 * 32 + 16) ^ st_swz);

    bf16x8 wf[2][8];
    #pragma unroll
    for (int cg = 0; cg < 2; ++cg) {
        const int cc = w * 64 + cg * 32 + nl;
        #pragma unroll
        for (int ks = 0; ks < 8; ++ks)
            wf[cg][ks] = *reinterpret_cast<const bf16x8*>(
                Wt + (size_t)cc * 128 + ks * 16 + hi * 8);
    }

    f32x16 binit[2];
    #pragma unroll
    for (int cg = 0; cg < 2; ++cg) {
        const int cc0 = w * 64 + cg * 32;
        #pragma unroll
        for (int r = 0; r < 16; ++r) {
            const int crow = (r & 3) + 8 * (r >> 2) + 4 * hi;
            const int cc = cc0 + crow;
            binit[cg][r] = (cc < 128) ? b1[cc] : 0.f;
        }
    }

    const int stride = gridDim.x - nscatter;
    int ng = blockIdx.x - nscatter;
    if (ng >= n_groups) return;

    float4 nz0, nz1, nz2, nz3;
    {
        int node = ng * 32 + st_node;
        node = (node < n_nodes) ? node : (n_nodes - 1);
        const float* zp = z + (size_t)node * HIDDEN + st_j2 * 16;
        nz0 = *reinterpret_cast<const float4*>(zp);
        nz1 = *reinterpret_cast<const float4*>(zp + 4);
        nz2 = *reinterpret_cast<const float4*>(zp + 8);
        nz3 = *reinterpret_cast<const float4*>(zp + 12);
    }

    while (ng < n_groups) {
        {
            uint4 A, B;
            A.x = cvt2(nz0.x, nz0.y); A.y = cvt2(nz0.z, nz0.w);
            A.z = cvt2(nz1.x, nz1.y); A.w = cvt2(nz1.z, nz1.w);
            B.x = cvt2(nz2.x, nz2.y); B.y = cvt2(nz2.z, nz2.w);
            B.z = cvt2(nz3.x, nz3.y); B.w = cvt2(nz3.z, nz3.w);
            *reinterpret_cast<uint4*>(Zt + st_addrA) = A;
            *reinterpret_cast<uint4*>(Zt + st_addrB) = B;
        }

        const int ngn = ng + stride;
        if (ngn < n_groups) {
            int node = ngn * 32 + st_node;
            node = (node < n_nodes) ? node : (n_nodes - 1);
            const float* zp = z + (size_t)node * HIDDEN + st_j2 * 16;
            nz0 = *reinterpret_cast<const float4*>(zp);
            nz1 = *reinterpret_cast<const float4*>(zp + 4);
            nz2 = *reinterpret_cast<const float4*>(zp + 8);
            nz3 = *reinterpret_cast<const float4*>(zp + 12);
        }

        __syncthreads();

        {
            const int rd_swz = (nl & 7) << 4;
            bf16x8 zf[8];
            #pragma unroll
            for (int ks = 0; ks < 8; ++ks) {
                const int off = ks * 32 + hi * 16;
                zf[ks] = *reinterpret_cast<const bf16x8*>(
                    Zt + nl * 256 + (off ^ rd_swz));
            }

            f32x16 acc0 = binit[0];
            f32x16 acc1 = binit[1];
            #pragma unroll
            for (int ks = 0; ks < 8; ++ks) {
                acc0 = __builtin_amdgcn_mfma_f32_32x32x16_bf16(wf[0][ks], zf[ks], acc0, 0, 0, 0);
                acc1 = __builtin_amdgcn_mfma_f32_32x32x16_bf16(wf[1][ks], zf[ks], acc1, 0, 0, 0);
            }

            const int swz = (nl & 15) << 3;
            #pragma unroll
            for (int g = 0; g < 4; ++g) {
                uint2 s0, s1;
                s0.x = cvt2(acc0[4 * g + 0], acc0[4 * g + 1]);
                s0.y = cvt2(acc0[4 * g + 2], acc0[4 * g + 3]);
                s1.x = cvt2(acc1[4 * g + 0], acc1[4 * g + 1]);
                s1.y = cvt2(acc1[4 * g + 2], acc1[4 * g + 3]);
                const int colb0 = w * 128 + g * 16 + hi * 8;
                const int colb1 = w * 128 + 64 + g * 16 + hi * 8;
                *reinterpret_cast<uint2*>(Sm + nl * 512 + (colb0 ^ swz)) = s0;
                *reinterpret_cast<uint2*>(Sm + nl * 512 + (colb1 ^ swz)) = s1;
            }
        }

        __syncthreads();

        {
            const int colb0 = (tid & 31) * 16;
            #pragma unroll
            for (int rep = 0; rep < 4; ++rep) {
                const int node_local = rep * 8 + (tid >> 5);
                const int swz = (node_local & 15) << 3;
                const uint2 g0 = *reinterpret_cast<const uint2*>(Sm + node_local * 512 + ((colb0) ^ swz));
                const uint2 g1 = *reinterpret_cast<const uint2*>(Sm + node_local * 512 + ((colb0 + 8) ^ swz));
                const int node = ng * 32 + node_local;
                if (node < n_nodes) {
                    uint4 o = { g0.x, g0.y, g1.x, g1.y };
                    *reinterpret_cast<uint4*>(UV + (size_t)node * 256 + (tid & 31) * 8) = o;
                }
            }
        }

        ng = ngn;
    }
}

// ---------------- K4: edge scoring ----------------
// score[e] = sum_j relu(u'[src][j] + v[dst][j]) * W2[j] + b2   (u' has b1)
static __device__ __forceinline__ float dot8(uint4 u, uint4 v, const float* w) {
    const uint32_t up[4] = { u.x, u.y, u.z, u.w };
    const uint32_t vp[4] = { v.x, v.y, v.z, v.w };
    float s = 0.f;
    #pragma unroll
    for (int p = 0; p < 4; ++p) {
        const float h0 = bf_lo(up[p]) + bf_lo(vp[p]);
        const float h1 = bf_hi(up[p]) + bf_hi(vp[p]);
        s = fmaf(fmaxf(h0, 0.f), w[2 * p], s);
        s = fmaf(fmaxf(h1, 0.f), w[2 * p + 1], s);
    }
    return s;
}
static __device__ __forceinline__ float red16(float s) {
    s += __shfl_xor(s, 1, 64); s += __shfl_xor(s, 2, 64);
    s += __shfl_xor(s, 4, 64); s += __shfl_xor(s, 8, 64);
    return s;
}

template <int PACKED>
__global__ __launch_bounds__(256, 4) void edge_score_t(
    const int2* __restrict__ sd, const int* __restrict__ org,
    const int* __restrict__ srcp, const int* __restrict__ dstp,
    const unsigned short* __restrict__ UV,
    const float* __restrict__ W2,
    const float* __restrict__ b2, float* __restrict__ outp, int n_edges)
{
    int vb = blockIdx.x;
    if (PACKED) {   // chunked bijective XCD swizzle (m204)
        const int nb = gridDim.x;
        const int q8 = nb >> 3, r8 = nb & 7;
        const int x = blockIdx.x & 7, i = blockIdx.x >> 3;
        vb = (x < r8 ? x * (q8 + 1) : r8 * (q8 + 1) + (x - r8) * q8) + i;
    }

    const int g = (vb * 256 + (int)threadIdx.x) >> 4;
    const int q = threadIdx.x & 15;
    const int e0 = g * EPG;
    if (e0 >= n_edges) return;

    const float4 w2a = *reinterpret_cast<const float4*>(W2 + q * 8);
    const float4 w2b = *reinterpret_cast<const float4*>(W2 + q * 8 + 4);
    const float wloc[8] = { w2a.x, w2a.y, w2a.z, w2a.w, w2b.x, w2b.y, w2b.z, w2b.w };
    const float bias = b2[0];

    const char* UVb = (const char*)UV;
    const uint32_t qo = (uint32_t)q * 16u;

    if (e0 + EPG - 1 < n_edges) {
        int sidx[EPG], didx[EPG];
        if (PACKED) {
            const int4 p0 = *reinterpret_cast<const int4*>(sd + e0);
            const int4 p1 = *reinterpret_cast<const int4*>(sd + e0 + 2);
            const int4 p2 = *reinterpret_cast<const int4*>(sd + e0 + 4);
            const int4 p3 = *reinterpret_cast<const int4*>(sd + e0 + 6);
            sidx[0]=p0.x; didx[0]=p0.y; sidx[1]=p0.z; didx[1]=p0.w;
            sidx[2]=p1.x; didx[2]=p1.y; sidx[3]=p1.z; didx[3]=p1.w;
            sidx[4]=p2.x; didx[4]=p2.y; sidx[5]=p2.z; didx[5]=p2.w;
            sidx[6]=p3.x; didx[6]=p3.y; sidx[7]=p3.z; didx[7]=p3.w;
        } else {
            const int4 sA = *reinterpret_cast<const int4*>(srcp + e0);
            const int4 sB = *reinterpret_cast<const int4*>(srcp + e0 + 4);
            const int4 dA = *reinterpret_cast<const int4*>(dstp + e0);
            const int4 dB = *reinterpret_cast<const int4*>(dstp + e0 + 4);
            sidx[0]=sA.x; sidx[1]=sA.y; sidx[2]=sA.z; sidx[3]=sA.w;
            sidx[4]=sB.x; sidx[5]=sB.y; sidx[6]=sB.z; sidx[7]=sB.w;
            didx[0]=dA.x; didx[1]=dA.y; didx[2]=dA.z; didx[3]=dA.w;
            didx[4]=dB.x; didx[5]=dB.y; didx[6]=dB.z; didx[7]=dB.w;
        }

        uint4 u[EPG], v[EPG];
        #pragma unroll
        for (int ii = 0; ii < EPG; ++ii) {
            u[ii] = *reinterpret_cast<const uint4*>(UVb + ((uint32_t)sidx[ii] * 512u + qo));
            v[ii] = *reinterpret_cast<const uint4*>(UVb + ((uint32_t)didx[ii] * 512u + 256u + qo));
        }
        __builtin_amdgcn_sched_barrier(0);

        float s[EPG];
        #pragma unroll
        for (int ii = 0; ii < EPG; ++ii) s[ii] = dot8(u[ii], v[ii], wloc);
        #pragma unroll
        for (int ii = 0; ii < EPG; ++ii) s[ii] = red16(s[ii]) + bias;

        if (q == 0) {
            if (PACKED) {
                const int4 o0 = *reinterpret_cast<const int4*>(org + e0);
                const int4 o1 = *reinterpret_cast<const int4*>(org + e0 + 4);
                outp[o0.x] = s[0]; outp[o0.y] = s[1];
                outp[o0.z] = s[2]; outp[o0.w] = s[3];
                outp[o1.x] = s[4]; outp[o1.y] = s[5];
                outp[o1.z] = s[6]; outp[o1.w] = s[7];
            } else {
                float4 oA = { s[0], s[1], s[2], s[3] };
                float4 oB = { s[4], s[5], s[6], s[7] };
                *reinterpret_cast<float4*>(outp + e0) = oA;
                *reinterpret_cast<float4*>(outp + e0 + 4) = oB;
            }
        }
    } else {
        for (int ii = 0; ii < EPG; ++ii) {
            const int e = e0 + ii;
            if (e >= n_edges) break;
            const int si = PACKED ? sd[e].x : srcp[e];
            const int di = PACKED ? sd[e].y : dstp[e];
            const uint4 uu = *reinterpret_cast<const uint4*>(UVb + ((uint32_t)si * 512u + qo));
            const uint4 vv = *reinterpret_cast<const uint4*>(UVb + ((uint32_t)di * 512u + 256u + qo));
            float s = red16(dot8(uu, vv, wloc));
            if (q == 0) {
                if (PACKED) outp[org[e]] = s + bias;
                else        outp[e] = s + bias;
            }
        }
    }
}

// ---- standalone transpose (no-sort fallback) ----
__global__ __launch_bounds__(256) void transpose_w1(
    const float* __restrict__ W1, unsigned short* __restrict__ Wt)
{
    const int t = blockIdx.x * 256 + threadIdx.x;
    if (t >= 4096) return;
    const int cc = t >> 4;
    const int kg = t & 15;
    const int ccol = cc & 127;
    const int kofs = (cc >= 128) ? 128 : 0;
    uint32_t u[4];
    #pragma unroll
    for (int p = 0; p < 4; ++p) {
        const float a = W1[(size_t)(kofs + kg * 8 + 2 * p) * 128 + ccol];
        const float b = W1[(size_t)(kofs + kg * 8 + 2 * p + 1) * 128 + ccol];
        u[p] = cvt2(a, b);
    }
    uint4 o = { u[0], u[1], u[2], u[3] };
    *reinterpret_cast<uint4*>(Wt + (size_t)cc * 128 + kg * 8) = o;
}

extern "C" void kernel_launch(void* const* d_in, const int* in_sizes, int n_in,
                              void* d_out, int out_size, void* d_ws, size_t ws_size,
                              hipStream_t stream) {
    const float* z  = (const float*)d_in[0];
    const int*   ei = (const int*)d_in[1];
    const float* W1 = (const float*)d_in[2];
    const float* b1 = (const float*)d_in[3];
    const float* W2 = (const float*)d_in[4];
    const float* b2 = (const float*)d_in[5];
    float* out = (float*)d_out;

    const int n_nodes = in_sizes[0] / HIDDEN;
    const int n_edges = in_sizes[1] / 2;

    int sh = 0;
    while (((unsigned)(n_nodes - 1) >> sh) >= NBUK) sh++;

    // ---- workspace layout ----
    char* wsp = (char*)d_ws;
    size_t off = 0;
    auto alloc = [&](size_t bytes) -> char* {
        char* p = wsp + off;
        off = (off + bytes + 255) & ~(size_t)255;
        return p;
    };
    unsigned short* UV = (unsigned short*)alloc((size_t)n_nodes * 256 * 2);
    unsigned short* Wt = (unsigned short*)alloc(256 * 128 * 2);
    int*  h      = (int*)alloc((size_t)NBUK * NBLK_SORT * 4);
    int*  rowtot = (int*)alloc((size_t)NBUK * 4);
    int2* sd     = (int2*)alloc((size_t)n_edges * 8);
    int*  org    = (int*)alloc((size_t)n_edges * 4);
    const bool do_sort = ws_size >= off;

    const int n_groups = (n_nodes + 31) / 32;
    const int groups = (n_edges + EPG - 1) / EPG;
    const int eblocks = (groups * 16 + 255) / 256;

    if (do_sort) {
        const int chunk = (n_edges + NBLK_SORT - 1) / NBLK_SORT;
        // K1: hist || transpose
        k1_hist_transpose<<<NBLK_SORT + 16, 256, 0, stream>>>(
            ei, h, n_edges, chunk, sh, W1, Wt);
        // K2: scanP1 (fast, standalone)
        scanP1<<<NBUK, NBLK_SORT, 0, stream>>>(h, rowtot);
        // K3: scatter || precompute
        {
            const int pblocks = n_groups < 1280 ? n_groups : 1280;
            k3_scatter_precompute<<<NBLK_SORT + pblocks, 256, 0, stream>>>(
                ei, h, rowtot, sd, org, n_edges, chunk, sh, NBLK_SORT,
                z, Wt, b1, UV, n_nodes, n_groups);
        }
        // K4: edge scoring
        edge_score_t<1><<<eblocks, 256, 0, stream>>>(sd, org, nullptr, nullptr, UV,
                                                     W2, b2, out, n_edges);
    } else {
        // fallback: transpose -> precompute (no scatter role) -> direct edge
        transpose_w1<<<16, 256, 0, stream>>>(W1, Wt);
        {
            const int pblocks = n_groups < 1280 ? n_groups : 1280;
            k3_scatter_precompute<<<pblocks, 256, 0, stream>>>(
                nullptr, nullptr, nullptr, nullptr, nullptr, 0, 0, sh, 0,
                z, Wt, b1, UV, n_nodes, n_groups);
        }
        edge_score_t<0><<<eblocks, 256, 0, stream>>>(nullptr, nullptr, ei, ei + n_edges,
                                                     UV, W2, b2, out, n_edges);
    }
}